// Round 12
// baseline (2269.440 us; speedup 1.0000x reference)
//
#include <hip/hip_runtime.h>

#define B_ 16
#define N_ 1024
#define M_ 4096
#define D_ 64
#define NTW 8                          // DP waves per batch pipeline
#define TROWS_ 1112                    // padded skewed rows per 128-col tile
#define TILEF_ ((size_t)TROWS_ * 128)  // floats per tile buffer
#define TSBW_ ((size_t)136 * 64)       // dec u32 words per tile (8704)
#define BTP_ 192                       // backtrack window pairs (384 cells)

__device__ __forceinline__ float finf() { return __builtin_inff(); }

// wave-wide shift right by 1 lane; lane 0 gets old (0), always select-overridden.
__device__ __forceinline__ float wave_shr1(float x) {
  return __int_as_float(__builtin_amdgcn_update_dpp(
      0, __float_as_int(x), 0x138, 0xF, 0xF, false));
}
__device__ __forceinline__ float rdlane(float v, int l) {
  return __int_as_float(__builtin_amdgcn_readlane(__float_as_int(v), l));
}

// ---------------------------------------------------------------------------
// Fused per-chunk kernel. Blocks [0,16): DP (one batch each). Blocks
// [16,272): GEMM producers for the SAME chunk — each 512-thread WG is two
// 256-thread halves, one (256col-group, 128-row band) each, writing Cs
// skewed for cpl=2 (cell (i,ctt) -> CsT[(i+(ctt>>1))*128+ctt]) and
// release-signaling flags[b][tb][band] = chunk+1. DP acquires flags at band
// crossings (first need: refills reach row 128 at sb=104).
// ---------------------------------------------------------------------------
__global__ __launch_bounds__(512) void fused_kernel(
    const float* __restrict__ x, const float* __restrict__ y,
    float* __restrict__ Cs, unsigned int* __restrict__ dec,
    const float* __restrict__ carryIn, float* __restrict__ carryOut,
    float* __restrict__ partV, int* __restrict__ partJ,
    int* __restrict__ flags, int chunk, int hasCarry) {
  __shared__ float ring[NTW - 1][1024];
  __shared__ float cring[1024];
  __shared__ int prog[NTW - 1];
  __shared__ float redV[NTW];
  __shared__ int redJ[NTW];
  __shared__ float sx2[256];
  const int token = chunk + 1;

  if (blockIdx.x >= 16) {
    // ---------------- GEMM producer path ----------------
    const int gid = blockIdx.x - 16;
    const int tb = gid & 3;           // 256-col group within chunk
    const int bp = (gid >> 2) & 3;    // band pair
    const int b = gid >> 4;           // batch
    const int h = threadIdx.x >> 8;   // half
    const int tt = threadIdx.x & 255;
    const int band = bp * 2 + h;
    const int lane = tt & 63;
    const int wid = tt >> 6;
    const int ct = wid * 64 + lane;          // col in 256-group
    const int j = chunk * 1024 + tb * 256 + ct;
    const int tileIdx = tb * 2 + (ct >> 7);  // 128-col tile (0..7)
    const int ctt = ct & 127;
    const int l = ctt >> 1;
    float* CsT = Cs + (size_t)(b * 8 + tileIdx) * TILEF_;
    const int ibeg = band * 128;

    if (tt < 128) {  // x2 for this half's 128 rows -> LDS
      const float4* xr = (const float4*)(x + ((size_t)b * N_ + ibeg + tt) * D_);
      float s = 0.f;
#pragma unroll
      for (int e = 0; e < D_ / 4; ++e) {
        float4 v = xr[e];
        s += v.x * v.x + v.y * v.y + v.z * v.z + v.w * v.w;
      }
      sx2[h * 128 + tt] = s;
    }

    const float4* yrow = (const float4*)(y + ((size_t)b * M_ + j) * D_);
    float4 yr[D_ / 4];
#pragma unroll
    for (int e = 0; e < D_ / 4; ++e) yr[e] = yrow[e];
    float y2 = 0.f;
#pragma unroll
    for (int e = 0; e < D_ / 4; ++e)
      y2 += yr[e].x * yr[e].x + yr[e].y * yr[e].y + yr[e].z * yr[e].z +
            yr[e].w * yr[e].w;
    __syncthreads();

    for (int i = ibeg; i < ibeg + 128; ++i) {
      const float4* xr = (const float4*)(x + ((size_t)b * N_ + i) * D_);
      float acc = 0.f;
#pragma unroll
      for (int e = 0; e < D_ / 4; ++e) {
        float4 xv = xr[e];
        acc += xv.x * yr[e].x + xv.y * yr[e].y + xv.z * yr[e].z + xv.w * yr[e].w;
      }
      CsT[(size_t)(i + l) * 128 + ctt] = sx2[h * 128 + (i - ibeg)] + y2 - 2.f * acc;
    }
    __syncthreads();
    if (tt == 0) {
      __threadfence();
      __hip_atomic_store(&flags[(b * 4 + tb) * 8 + band], token,
                         __ATOMIC_RELEASE, __HIP_MEMORY_SCOPE_AGENT);
    }
    return;
  }

  // ---------------- DP consumer path (R11 body + flag gates) ----------------
  const int b = blockIdx.x;
  const int t = threadIdx.x;
  const int lane = t & 63;
  const int W = t >> 6;
  volatile int* vProg = prog;

  if (t < NTW - 1) prog[t] = -1;
  const float* cIn = carryIn + b * N_;
  if (hasCarry && t < 256) ((float4*)cring)[t] = ((const float4*)cIn)[t];
  __syncthreads();

  const int* fl = flags + (b * 4 + (W >> 1)) * 8;
  while (__hip_atomic_load(&fl[0], __ATOMIC_ACQUIRE,
                           __HIP_MEMORY_SCOPE_AGENT) != token)
    __builtin_amdgcn_s_sleep(8);

  const float INF = finf();
  const float* tileBase = Cs + (size_t)(b * 8 + W) * TILEF_;
  const float* loadP = tileBase + 16 * 128;
  const int tileG = chunk * 8 + W;
  unsigned int* decW = dec + (size_t)(b * 32 + tileG) * TSBW_ + lane;
  float* carryB = carryOut + b * N_;
  const int jbase = tileG * 128 + lane * 2;
  const float* ringR = ring[W > 0 ? W - 1 : 0];
  volatile float* ringW = ring[W < NTW - 1 ? W : 0];
  const bool doCarry = (W == NTW - 1) && (chunk < 3);

  float2 cc0 = ((const float2*)(tileBase + 0 * 128))[lane];
  float2 cc1 = ((const float2*)(tileBase + 1 * 128))[lane];
  float2 cc2 = ((const float2*)(tileBase + 2 * 128))[lane];
  float2 cc3 = ((const float2*)(tileBase + 3 * 128))[lane];
  float2 cc4 = ((const float2*)(tileBase + 4 * 128))[lane];
  float2 cc5 = ((const float2*)(tileBase + 5 * 128))[lane];
  float2 cc6 = ((const float2*)(tileBase + 6 * 128))[lane];
  float2 cc7 = ((const float2*)(tileBase + 7 * 128))[lane];
  float2 cc8 = ((const float2*)(tileBase + 8 * 128))[lane];
  float2 cc9 = ((const float2*)(tileBase + 9 * 128))[lane];
  float2 cc10 = ((const float2*)(tileBase + 10 * 128))[lane];
  float2 cc11 = ((const float2*)(tileBase + 11 * 128))[lane];
  float2 cc12 = ((const float2*)(tileBase + 12 * 128))[lane];
  float2 cc13 = ((const float2*)(tileBase + 13 * 128))[lane];
  float2 cc14 = ((const float2*)(tileBase + 14 * 128))[lane];
  float2 cc15 = ((const float2*)(tileBase + 15 * 128))[lane];

  float edgeVec = INF, ePrev = INF;
  float up0 = 0.f, up1 = 0.f;
  float sh1 = INF, sh2 = INF;
  float fin0 = INF, fin1 = INF;
  float ebuf[8];

#define BLOCKHEAD()                                                           \
  {                                                                           \
    if ((sb & 127) == 104 && sb < 1000) { /* gemm band gate: rows<=sb+23 */   \
      const int kb = (sb + 24) >> 7;                                          \
      while (__hip_atomic_load(&fl[kb], __ATOMIC_ACQUIRE,                     \
                               __HIP_MEMORY_SCOPE_AGENT) != token)            \
        __builtin_amdgcn_s_sleep(8);                                          \
    }                                                                         \
    if (sb < N_) {                                                            \
      if (W > 0) {                                                            \
        int tgt = sb + 7;                                                     \
        if (tgt > N_ - 1) tgt = N_ - 1;                                       \
        while (vProg[W - 1] < tgt) __builtin_amdgcn_s_sleep(1);               \
        asm volatile("" ::: "memory");                                        \
        edgeVec = ringR[(sb - 1 + lane) & 1023];                              \
      } else if (hasCarry) {                                                  \
        edgeVec = cring[(sb - 1 + lane) & 1023];                              \
      }                                                                       \
      ePrev = rdlane(edgeVec, 0);                                             \
    }                                                                         \
  }

#define DPSTEP(KK, CCV, ROW0, FIN)                                           \
  {                                                                          \
    const float eL = rdlane(edgeVec, (KK) + 1);                              \
    const bool l0 = (lane == 0);                                             \
    const float left0 = l0 ? eL : sh1;                                       \
    const float diag0 = l0 ? ePrev : sh2;                                    \
    ePrev = eL;                                                              \
    float m = fminf(up0, left0);                                             \
    float bv = fminf(diag0, m);                                              \
    unsigned int pk = (diag0 <= m) ? 0u : ((up0 <= left0) ? 1u : 2u);        \
    if (ROW0) bv = (sb + (KK) == lane) ? 0.f : bv;                           \
    const float D0 = CCV.x + bv;                                             \
    m = fminf(up1, D0);                                                      \
    bv = fminf(up0, m);                                                      \
    pk |= ((up0 <= m) ? 0u : ((up1 <= D0) ? 1u : 2u)) << 2;                  \
    if (ROW0) bv = (sb + (KK) == lane) ? 0.f : bv;                           \
    const float D1 = CCV.y + bv;                                             \
    if ((KK) == 0) pkb = pk;                                                 \
    else pkb |= pk << (4 * (KK));                                            \
    if ((KK) == 7) decW[0] = pkb;                                            \
    ebuf[(KK)] = D1;                                                         \
    if (FIN) {                                                               \
      const bool lr = (sb + (KK) == 1023 + lane);                            \
      fin0 = lr ? D0 : fin0;                                                 \
      fin1 = lr ? D1 : fin1;                                                 \
    }                                                                        \
    sh2 = sh1;                                                               \
    sh1 = wave_shr1(D1);                                                     \
    up0 = D0; up1 = D1;                                                      \
    CCV = ((const float2*)(loadP + (KK) * 128))[lane];                       \
  }

#define BLOCKEND()                                                           \
  {                                                                          \
    const int rb = sb - 63;                                                  \
    if (W < NTW - 1) {                                                       \
      if (lane == 63 && rb > -8) {                                           \
        _Pragma("unroll") for (int k = 0; k < 8; ++k) {                      \
          const int r = rb + k;                                              \
          if ((unsigned)r < (unsigned)N_) ringW[r] = ebuf[k];                \
        }                                                                    \
        __builtin_amdgcn_s_waitcnt(0xC07F);                                  \
        int p = rb + 7;                                                      \
        if (p > N_ - 1) p = N_ - 1;                                          \
        if (p >= 0) vProg[W] = p;                                            \
      }                                                                      \
    } else if (doCarry) {                                                    \
      if (lane == 63 && rb > -8) {                                           \
        _Pragma("unroll") for (int k = 0; k < 8; ++k) {                      \
          const int r = rb + k;                                              \
          if ((unsigned)r < (unsigned)N_) carryB[r] = ebuf[k];               \
        }                                                                    \
      }                                                                      \
    }                                                                        \
    loadP += 8 * 128;                                                        \
    decW += 64;                                                              \
  }

#define STEP8A(R0, FN)                                                       \
  DPSTEP(0, cc0, R0, FN) DPSTEP(1, cc1, R0, FN) DPSTEP(2, cc2, R0, FN)       \
  DPSTEP(3, cc3, R0, FN) DPSTEP(4, cc4, R0, FN) DPSTEP(5, cc5, R0, FN)       \
  DPSTEP(6, cc6, R0, FN) DPSTEP(7, cc7, R0, FN)
#define STEP8B(R0, FN)                                                       \
  DPSTEP(0, cc8, R0, FN) DPSTEP(1, cc9, R0, FN) DPSTEP(2, cc10, R0, FN)      \
  DPSTEP(3, cc11, R0, FN) DPSTEP(4, cc12, R0, FN) DPSTEP(5, cc13, R0, FN)    \
  DPSTEP(6, cc14, R0, FN) DPSTEP(7, cc15, R0, FN)

#define ITER16(R0, FN)                                                       \
  {                                                                          \
    BLOCKHEAD();                                                             \
    { unsigned int pkb; STEP8A(R0, FN) }                                     \
    BLOCKEND();                                                              \
    sb += 8;                                                                 \
    BLOCKHEAD();                                                             \
    { unsigned int pkb; STEP8B(R0, FN) }                                     \
    BLOCKEND();                                                              \
    sb += 8;                                                                 \
  }

  int sb = 0;
  for (int it = 0; it < 4; ++it) ITER16(1, 0);    // sb 0..63: row-0 live
  for (int it = 0; it < 59; ++it) ITER16(0, 0);   // sb 64..1007: main
  for (int it = 0; it < 5; ++it) ITER16(0, 1);    // sb 1008..1087: fin
#undef DPSTEP
#undef STEP8A
#undef STEP8B
#undef ITER16
#undef BLOCKHEAD
#undef BLOCKEND

  float mv = fin0; int mj = jbase;
  if (fin1 < mv) { mv = fin1; mj = jbase + 1; }
#pragma unroll
  for (int off = 32; off > 0; off >>= 1) {
    const float ov = __shfl_down(mv, off);
    const int oj = __shfl_down(mj, off);
    if (ov < mv || (ov == mv && oj < mj)) { mv = ov; mj = oj; }
  }
  if (lane == 0) { redV[W] = mv; redJ[W] = mj; }
  __syncthreads();
  if (t == 0) {
    float bm = redV[0]; int bj = redJ[0];
#pragma unroll
    for (int w = 1; w < NTW; ++w)
      if (redV[w] < bm) { bm = redV[w]; bj = redJ[w]; }
    partV[b * 4 + chunk] = bm;
    partJ[b * 4 + chunk] = bj;
  }
}

// ---------------------------------------------------------------------------
// Backtrack: 512 threads = 8 subs/row x 64 rows per super-step; also copies
// x_t -> w_ts output (prep kernel folded in). Cell (r, j): pair p = j>>1,
// tile = p>>6, l = p&63, s = r+l -> nibble (s&7) of
// dw[tile*TSBW + (s>>3)*64 + l], bit pair (j&1)*2.
// ---------------------------------------------------------------------------
__global__ __launch_bounds__(512) void backtrack_kernel(
    const unsigned int* __restrict__ dec, const float* __restrict__ partV,
    const int* __restrict__ partJ, const float* __restrict__ y_t,
    const float* __restrict__ x_t, float* __restrict__ w_ts,
    float* __restrict__ w_vs, float* __restrict__ cost_out) {
  const int b = blockIdx.x;
  const int t = threadIdx.x;
  const int rowIdx = t >> 3;
  const int sub = t & 7;
  __shared__ unsigned short tab[64][BTP_ * 2 + 2];
  __shared__ unsigned short lastv[64][8];
  __shared__ int st_i, st_j;
  __shared__ int jrow[65];
  const unsigned int* dw = dec + (size_t)b * 32 * TSBW_;
  const float* yt = y_t + b * M_;
  float* wv = w_vs + b * N_;

  w_ts[b * N_ + t] = x_t[b * N_ + t];
  w_ts[b * N_ + t + 512] = x_t[b * N_ + t + 512];

  if (t == 0) {
    float bc = finf(); int bj = 0;
    for (int c = 0; c < 4; ++c) {  // chunks ascend in j: strict < keeps first
      const float v = partV[b * 4 + c];
      if (v < bc) { bc = v; bj = partJ[b * 4 + c]; }
    }
    cost_out[b] = bc;
    st_i = N_ - 1;
    st_j = bj;
    wv[N_ - 1] = yt[bj];
  }
  for (;;) {
    __syncthreads();
    const int i = st_i, j = st_j;
    if (i <= 0) break;
    int plo = (j >> 1) - (BTP_ - 1);
    if (plo < 0) plo = 0;
    const int r = i - rowIdx;
    const int cbase = sub * 48;  // 24 pairs = 48 cells per sub-thread
    int patchEnd = 0;
    if (r >= 1) {
      unsigned char nb[24];
      const int p0 = plo + sub * 24;
#pragma unroll
      for (int k = 0; k < 24; ++k) {
        const int p = p0 + k;
        const int l = p & 63;
        const int s = r + l;
        const unsigned int word =
            dw[(size_t)(p >> 6) * TSBW_ + (size_t)(s >> 3) * 64 + l];
        nb[k] = (word >> (4 * (s & 7))) & 15u;
      }
      unsigned int run = 0xFFFF;
      int fs = -1;
#pragma unroll
      for (int k = 0; k < 24; ++k) {
        const unsigned int nib = nb[k];
#pragma unroll
        for (int p2 = 0; p2 < 2; ++p2) {
          const unsigned int code = (nib >> (p2 * 2)) & 3u;
          const int cloc = 2 * k + p2;
          if (code != 2u) {
            run = (unsigned int)(((cbase + cloc) << 2) | code);
            if (fs < 0) fs = cloc;
          }
          tab[rowIdx][cbase + cloc] = (unsigned short)run;
        }
      }
      lastv[rowIdx][sub] = (unsigned short)run;
      patchEnd = (fs < 0) ? 48 : fs;
    }
    __syncthreads();
    if (r >= 1 && sub > 0 && patchEnd > 0) {
      unsigned short inc = 0xFFFF;
      for (int s2 = 0; s2 < sub; ++s2) {
        const unsigned short lv = lastv[rowIdx][s2];
        if (lv != 0xFFFF) inc = lv;
      }
      if (inc != 0xFFFF) {
        for (int k = 0; k < patchEnd; ++k) tab[rowIdx][cbase + k] = inc;
      }
    }
    __syncthreads();
    if (t == 0) {
      const int base = plo << 1;
      int rr = i, cj = j;
      while (rr >= 1 && (i - rr) < 64) {
        const int l = i - rr;
        const int c = cj - base;
        if (c < 0) break;  // window exhausted; restart super-step
        const unsigned short v = tab[l][c];
        if (v == 0xFFFF) { cj = base - 1; break; }  // left-run exits window
        cj = base + (int)(v >> 2) - (((v & 3) == 0) ? 1 : 0);
        --rr;
        jrow[i - rr] = cj;
      }
      st_i = rr;
      st_j = cj;
    }
    __syncthreads();
    const int cnt = i - st_i;
    if (t < cnt) wv[i - 1 - t] = yt[jrow[t + 1]];
  }
}

// ---------------------------------------------------------------------------
extern "C" void kernel_launch(void* const* d_in, const int* in_sizes, int n_in,
                              void* d_out, int out_size, void* d_ws, size_t ws_size,
                              hipStream_t stream) {
  const float* x = (const float*)d_in[0];
  const float* y = (const float*)d_in[1];
  const float* x_t = (const float*)d_in[2];
  const float* y_t = (const float*)d_in[3];

  float* out_cost = (float*)d_out;      // [B_]
  float* out_wts = out_cost + B_;       // [B_][N_]
  float* out_wvs = out_wts + B_ * N_;   // [B_][N_]

  const size_t csBytes = (size_t)B_ * 8 * TILEF_ * 4;   // 72.9 MB (one chunk)
  const size_t decBytes = (size_t)B_ * 32 * TSBW_ * 4;  // 17.8 MB

  char* ws = (char*)d_ws;
  float* Cs = (float*)ws;
  unsigned int* dec = (unsigned int*)(ws + csBytes);
  float* carryA = (float*)(ws + csBytes + decBytes);
  float* carryB = carryA + B_ * N_;
  float* partV = carryB + B_ * N_;
  int* partJ = (int*)(partV + B_ * 4);
  int* flags = partJ + B_ * 4;  // [16][4][8] tokens; 0xAAAAAAAA-safe

  float* cbuf[2] = {carryA, carryB};
  for (int c = 0; c < 4; ++c) {
    const float* cin = cbuf[(c + 1) & 1];
    float* cout = cbuf[c & 1];
    fused_kernel<<<dim3(16 + 256), 512, 0, stream>>>(
        x, y, Cs, dec, cin, cout, partV, partJ, flags, c, c > 0 ? 1 : 0);
  }

  backtrack_kernel<<<dim3(B_), 512, 0, stream>>>(dec, partV, partJ, y_t, x_t,
                                                 out_wts, out_wvs, out_cost);
}